// Round 12
// baseline (164.606 us; speedup 1.0000x reference)
//
#include <hip/hip_runtime.h>
#include <hip/hip_bf16.h>
#include <math.h>

typedef __bf16 bf16_8 __attribute__((ext_vector_type(8)));
typedef float f32x4 __attribute__((ext_vector_type(4)));

#define D_ 256
#define S_ 128
#define E_ 512
#define MPE_ 4096
#define B_ 2
#define N_ 4096
#define M_TOT (B_*N_)   // 8192

__device__ __forceinline__ ushort f2b(float f) {
  union { float f; uint u; } x; x.f = f;
  uint r = (x.u + 0x7FFFu + ((x.u >> 16) & 1u)) >> 16;
  return (ushort)r;
}
__device__ __forceinline__ float b2f(ushort b) {
  union { uint u; float f; } x; x.u = ((uint)b) << 16;
  return x.f;
}

// ---------------- LayerNorm: one wave per row ----------------
__global__ __launch_bounds__(256) void ln_kernel(const float* __restrict__ q,
    const float* __restrict__ w, const float* __restrict__ b,
    ushort* __restrict__ x) {
  int wid = threadIdx.x >> 6, lane = threadIdx.x & 63;
  int row = blockIdx.x * 4 + wid;
  const float* qr = q + (size_t)row * D_;
  float4 v = *(const float4*)(qr + lane * 4);
  float s  = v.x + v.y + v.z + v.w;
  float ss = v.x*v.x + v.y*v.y + v.z*v.z + v.w*v.w;
  #pragma unroll
  for (int off = 32; off; off >>= 1) {
    s  += __shfl_xor(s, off);
    ss += __shfl_xor(ss, off);
  }
  float mu   = s * (1.0f / 256.0f);
  float var  = ss * (1.0f / 256.0f) - mu * mu;
  float rstd = rsqrtf(var + 1e-5f);
  ushort4 o;
  float vv[4] = {v.x, v.y, v.z, v.w};
  ushort ot[4];
  #pragma unroll
  for (int j = 0; j < 4; ++j) {
    int c = lane * 4 + j;
    ot[j] = f2b((vv[j] - mu) * rstd * w[c] + b[c]);
  }
  o.x = ot[0]; o.y = ot[1]; o.z = ot[2]; o.w = ot[3];
  *(ushort4*)(x + (size_t)row * D_ + lane * 4) = o;
}

// ---------------- prep: all 4 weight transposes + wrep in ONE launch ----------------
__global__ __launch_bounds__(256) void prep_kernel(
    const float* __restrict__ Wu, const float* __restrict__ Wv,
    const float* __restrict__ Wb, const float* __restrict__ Wo,
    const float* __restrict__ w_rel,
    ushort* __restrict__ WUT, ushort* __restrict__ WVT,
    ushort* __restrict__ WBT, ushort* __restrict__ WOT,
    float* __restrict__ wrep) {
  int blk = blockIdx.x, tid = threadIdx.x;
  if (blk < 512) {
    int o = blk * 256 + tid; int c = o >> 8, r = o & 255;
    WUT[o] = f2b(Wu[r * 512 + c]);
  } else if (blk < 1024) {
    int o = (blk - 512) * 256 + tid; int c = o >> 8, r = o & 255;
    WVT[o] = f2b(Wv[r * 512 + c]);
  } else if (blk < 1152) {
    int o = (blk - 1024) * 256 + tid; int c = o >> 8, r = o & 255;
    WBT[o] = f2b(Wb[r * 128 + c]);
  } else if (blk < 1664) {
    int o = (blk - 1152) * 256 + tid; int c = o >> 9, r = o & 511;
    WOT[o] = f2b(Wo[r * 256 + c]);
  } else {
    int idx = (blk - 1664) * 256 + tid;
    int c = idx >> 13, i = idx & 8191;
    int s = i + c; if (s > 8190) s = 8190;
    wrep[idx] = w_rel[s];
  }
}

// ---------------- GEMM: A[M][K] bf16, Bt[N][K] bf16, tile 128x64, BK=64 ----------------
// EPI 0: silu -> bf16 row-major. EPI 1: +bias f32 row-major.
// EPI 2: silu -> bf16 in PV-FRAGMENT order:
//   VF[((b*64+t)*2+ks)*32 + e/16][ (kq*16 + e%16)*8 + j ]  (t,nn from row; ks,kq,j from nn)
template<int EPI>
__global__ __launch_bounds__(256) void gemm_kernel(
    const ushort* __restrict__ A, const ushort* __restrict__ Bt,
    const float* __restrict__ bias, void* __restrict__ out,
    int M, int N, int K) {
  __shared__ alignas(16) ushort As[128 * 64];
  __shared__ alignas(16) ushort Bs[64 * 64];
  int tid = threadIdx.x;
  int lane = tid & 63, wid = tid >> 6;
  int m0 = blockIdx.x * 128, n0 = blockIdx.y * 64;
  int r16 = lane & 15, kq = lane >> 4;
  f32x4 acc[2][4] = {};
  for (int k0 = 0; k0 < K; k0 += 64) {
    __syncthreads();
    #pragma unroll
    for (int t = 0; t < 4; ++t) {
      int cid = tid + t * 256;
      int row = cid >> 3, c = cid & 7;
      uint4 d = *(const uint4*)(A + ((size_t)(m0 + row) * K + k0 + c * 8));
      *(uint4*)&As[row * 64 + ((c ^ (row & 7)) * 8)] = d;
    }
    #pragma unroll
    for (int t = 0; t < 2; ++t) {
      int cid = tid + t * 256;
      int row = cid >> 3, c = cid & 7;
      uint4 d = *(const uint4*)(Bt + ((size_t)(n0 + row) * K + k0 + c * 8));
      *(uint4*)&Bs[row * 64 + ((c ^ (row & 7)) * 8)] = d;
    }
    __syncthreads();
    #pragma unroll
    for (int ks = 0; ks < 2; ++ks) {
      bf16_8 af[2], bfr[4];
      int c = ks * 4 + kq;
      #pragma unroll
      for (int fm = 0; fm < 2; ++fm) {
        int r = wid * 32 + fm * 16 + r16;
        af[fm] = *(const bf16_8*)&As[r * 64 + ((c ^ (r & 7)) * 8)];
      }
      #pragma unroll
      for (int fn = 0; fn < 4; ++fn) {
        int r = fn * 16 + r16;
        bfr[fn] = *(const bf16_8*)&Bs[r * 64 + ((c ^ (r & 7)) * 8)];
      }
      #pragma unroll
      for (int fm = 0; fm < 2; ++fm)
        #pragma unroll
        for (int fn = 0; fn < 4; ++fn)
          acc[fm][fn] = __builtin_amdgcn_mfma_f32_16x16x32_bf16(af[fm], bfr[fn], acc[fm][fn], 0, 0, 0);
    }
  }
  #pragma unroll
  for (int fm = 0; fm < 2; ++fm)
    #pragma unroll
    for (int fn = 0; fn < 4; ++fn)
      #pragma unroll
      for (int reg = 0; reg < 4; ++reg) {
        int ml = wid * 32 + fm * 16 + kq * 4 + reg;
        int nl = fn * 16 + r16;
        size_t gm = m0 + ml, gn = n0 + nl;
        float val = acc[fm][fn][reg] + bias[gn];
        if (EPI == 0) {
          float y = val / (1.0f + expf(-val));
          ((ushort*)out)[gm * N + gn] = f2b(y);
        } else if (EPI == 2) {
          float y = val / (1.0f + expf(-val));
          int bb = (int)(gm >> 12), n = (int)(gm & 4095);
          int t = n >> 6, nn = n & 63;
          int ks2 = nn >> 5, kq2 = (nn >> 3) & 3, j = nn & 7;
          size_t addr = ((size_t)((bb * 64 + t) * 2 + ks2) * 32 + (gn >> 4)) * 512
                      + (kq2 * 16 + (gn & 15)) * 8 + j;
          ((ushort*)out)[addr] = f2b(y);
        } else {
          ((float*)out)[gm * N + gn] = val;
        }
      }
}

// ---------------- RoPE: Q row-major; K in QK A-FRAGMENT order ----------------
// KF[((b*64+t)*16 + wn*4 + ks)*512 + kq*128 + r16*8 + j]  (pre-scaled by 1/64)
__global__ __launch_bounds__(256) void rope_kernel(const ushort* __restrict__ base,
    const float* __restrict__ qw, const float* __restrict__ qb,
    const float* __restrict__ kw, const float* __restrict__ kb,
    ushort* __restrict__ Q, ushort* __restrict__ KF) {
  int g = blockIdx.x * 256 + threadIdx.x;
  int row = g >> 6, i = g & 63;
  int n = row & (N_ - 1);
  float invf = powf(10000.0f, -(float)i * (1.0f / 64.0f));
  float sv, cv;
  sincosf((float)n * invf, &sv, &cv);
  const float sc = 0.015625f;   // 1/64; (1/64)^2 = 1/MPE
  float b1 = b2f(base[row * S_ + i]), b2 = b2f(base[row * S_ + 64 + i]);
  float x1q = b1 * qw[i] + qb[i], x2q = b2 * qw[64 + i] + qb[64 + i];
  Q[row * S_ + i]      = f2b((x1q * cv - x2q * sv) * sc);
  Q[row * S_ + 64 + i] = f2b((x2q * cv + x1q * sv) * sc);
  float x1k = b1 * kw[i] + kb[i], x2k = b2 * kw[64 + i] + kb[64 + i];
  float k1 = (x1k * cv - x2k * sv) * sc;
  float k2 = (x2k * cv + x1k * sv) * sc;
  int bb = row >> 12, nn = n & 63, t = n >> 6;
  int wn = nn >> 4, r16 = nn & 15;
  size_t kbase = ((size_t)((bb * 64 + t) * 16 + wn * 4)) * 512 + r16 * 8;
  int ks1 = i >> 5, kq1 = (i >> 3) & 3, j = i & 7;
  KF[kbase + ks1 * 512 + kq1 * 128 + j] = f2b(k1);            // k = i
  KF[kbase + (2 + ks1) * 512 + kq1 * 128 + j] = f2b(k2);      // k = i + 64
}

// ---------------- fused attention: K/V register-direct from fragment-order global ----------------
// grid (64 m-tiles of 64, 4 e-chunks of 128, 2 b) = 512 blocks, 256 thr (4 waves),
// 2 blocks/CU. NO K/V LDS: kf/vf are coalesced dwordx4 loads from KF/VF (L1/L2).
// LDS holds only P (double-buffered, 16 KB). One lgkm-only barrier per iter;
// vf(t) issued in body(t), consumed in body(t+1) -> latency rides across barrier.
__global__ __launch_bounds__(256, 2) void attn_kernel(
    const ushort* __restrict__ Q, const ushort* __restrict__ KF,
    const ushort* __restrict__ VF, const ushort* __restrict__ U,
    const float* __restrict__ wrep, ushort* __restrict__ KVU) {
  __shared__ alignas(16) ushort Pb[2][64 * 64];    // 16 KB
  const int tid = threadIdx.x, lane = tid & 63, wid = tid >> 6;
  const int b = blockIdx.z, m0 = blockIdx.x * 64;
  const int r16 = lane & 15, kq = lane >> 4;
  const int wn = wid;                       // QK: 16n strip per wave, all 64m
  const int wpm = wid >> 1, wpe = wid & 1;  // PV: 2m x 2e

  // bias: w_rel idx = 4095 + (64t + 16wn + 4kq + rg) - (m0 + 16fm + r16)
  const int bbase = 4095 + 16 * wn + 4 * kq - m0 - r16;
  const int csel = bbase & 3;
  const float* wrow = wrep + csel * 8192 + (bbase - csel);

  // Q fragments: 64 m-rows x 128 k per wave (B-operand: col=m)
  bf16_8 qf[4][4];
  #pragma unroll
  for (int fm = 0; fm < 4; ++fm)
    #pragma unroll
    for (int ks = 0; ks < 4; ++ks)
      qf[fm][ks] = *(const bf16_8*)(Q +
          ((size_t)(b * N_ + m0 + fm * 16 + r16) * S_ + ks * 32 + kq * 8));

  const ushort* kfb = KF + ((size_t)(b * 64) * 16 + wn * 4) * 512 + lane * 8;
  const ushort* vfb = VF + ((size_t)(b * 64) * 2 * 32 + blockIdx.y * 8 + wpe * 4) * 512 + lane * 8;

  uint4 kf[4], vf[8];
  float4 b4[4];
  f32x4 pv[2][4] = {};

  auto issue_kf = [&](int t) {
    #pragma unroll
    for (int ks = 0; ks < 4; ++ks)
      kf[ks] = *(const uint4*)(kfb + ((size_t)t * 16 + ks) * 512);
  };
  auto issue_vf = [&](int t) {
    #pragma unroll
    for (int ks = 0; ks < 2; ++ks)
      #pragma unroll
      for (int fe = 0; fe < 4; ++fe)
        vf[ks * 4 + fe] = *(const uint4*)(vfb + ((size_t)t * 64 + ks * 32 + fe) * 512);
  };
  auto issue_bias = [&](int t) {
    #pragma unroll
    for (int fm = 0; fm < 4; ++fm)
      b4[fm] = *(const float4*)(wrow + 64 * t - 16 * fm);
  };

  auto do_pv = [&](int pi) {
    const char* psb = (const char*)&Pb[pi][0];
    __builtin_amdgcn_s_setprio(1);
    #pragma unroll
    for (int ks = 0; ks < 2; ++ks) {
      bf16_8 pa[2];
      #pragma unroll
      for (int fm = 0; fm < 2; ++fm) {
        int r = wpm * 32 + fm * 16 + r16;
        pa[fm] = *(const bf16_8*)(psb + ((r * 128 + ks * 64 + kq * 16) ^ ((r & 7) << 4)));
      }
      #pragma unroll
      for (int fe = 0; fe < 4; ++fe) {
        bf16_8 vfr = *(const bf16_8*)&vf[ks * 4 + fe];
        #pragma unroll
        for (int fm = 0; fm < 2; ++fm)
          pv[fm][fe] = __builtin_amdgcn_mfma_f32_16x16x32_bf16(pa[fm], vfr, pv[fm][fe], 0, 0, 0);
      }
    }
    __builtin_amdgcn_s_setprio(0);
  };

  auto qk_transform = [&](int t) {
    f32x4 sacc[4] = {};
    __builtin_amdgcn_s_setprio(1);
    #pragma unroll
    for (int ks = 0; ks < 4; ++ks) {
      bf16_8 kfr = *(const bf16_8*)&kf[ks];
      #pragma unroll
      for (int fm = 0; fm < 4; ++fm)
        sacc[fm] = __builtin_amdgcn_mfma_f32_16x16x32_bf16(kfr, qf[fm][ks], sacc[fm], 0, 0, 0);
    }
    __builtin_amdgcn_s_setprio(0);
    char* psb = (char*)&Pb[t & 1][0];
    #pragma unroll
    for (int fm = 0; fm < 4; ++fm) {
      float t0 = fmaxf(sacc[fm][0] + b4[fm].x, 0.f); t0 *= t0;
      float t1 = fmaxf(sacc[fm][1] + b4[fm].y, 0.f); t1 *= t1;
      float t2 = fmaxf(sacc[fm][2] + b4[fm].z, 0.f); t2 *= t2;
      float t3 = fmaxf(sacc[fm][3] + b4[fm].w, 0.f); t3 *= t3;
      uint p01, p23;
      asm("v_cvt_pk_bf16_f32 %0, %1, %2" : "=v"(p01) : "v"(t0), "v"(t1));
      asm("v_cvt_pk_bf16_f32 %0, %1, %2" : "=v"(p23) : "v"(t2), "v"(t3));
      int mp = fm * 16 + r16;
      int nb2 = wn * 32 + kq * 8;
      uint2 pk; pk.x = p01; pk.y = p23;
      *(uint2*)(psb + ((mp * 128 + nb2) ^ ((mp & 7) << 4))) = pk;
    }
  };

  // body(0): no PV
  issue_kf(0); issue_bias(0); issue_vf(0);
  qk_transform(0);
  asm volatile("s_waitcnt lgkmcnt(0)" ::: "memory");
  __builtin_amdgcn_s_barrier();

  for (int t = 1; t < 64; ++t) {
    issue_kf(t); issue_bias(t);
    do_pv((t - 1) & 1);          // vf(t-1) regs + P(t-1) LDS
    issue_vf(t);                 // for next body; rides across barrier
    qk_transform(t);             // kf(t) regs -> P(t)
    asm volatile("s_waitcnt lgkmcnt(0)" ::: "memory");
    __builtin_amdgcn_s_barrier();
  }
  // drain: PV(63)
  do_pv(1);

  // ---- epilogue: KVU = bf16(u * pv) ----
  #pragma unroll
  for (int fm = 0; fm < 2; ++fm)
    #pragma unroll
    for (int fe = 0; fe < 4; ++fe)
      #pragma unroll
      for (int reg = 0; reg < 4; ++reg) {
        int ml = wpm * 32 + fm * 16 + kq * 4 + reg;
        size_t grow = (size_t)b * N_ + m0 + ml;
        size_t ge = (size_t)blockIdx.y * 128 + wpe * 64 + fe * 16 + r16;
        float uu = b2f(U[grow * E_ + ge]);
        KVU[grow * E_ + ge] = f2b(uu * pv[fm][fe][reg]);
      }
}

extern "C" void kernel_launch(void* const* d_in, const int* in_sizes, int n_in,
                              void* d_out, int out_size, void* d_ws, size_t ws_size,
                              hipStream_t stream) {
  const float* query = (const float*)d_in[0];
  const float* ln_w  = (const float*)d_in[1];
  const float* ln_b  = (const float*)d_in[2];
  const float* Wu    = (const float*)d_in[3];
  const float* bu    = (const float*)d_in[4];
  const float* Wv    = (const float*)d_in[5];
  const float* bv    = (const float*)d_in[6];
  const float* Wbase = (const float*)d_in[7];
  const float* bbase = (const float*)d_in[8];
  const float* q_w   = (const float*)d_in[9];
  const float* q_b   = (const float*)d_in[10];
  const float* k_w   = (const float*)d_in[11];
  const float* k_b   = (const float*)d_in[12];
  const float* w_rel = (const float*)d_in[13];
  const float* Wo    = (const float*)d_in[14];
  const float* bo    = (const float*)d_in[15];
  float* out = (float*)d_out;

  char* ws = (char*)d_ws;
  ushort* X    = (ushort*)(ws);                     // 4 MB
  ushort* U    = (ushort*)(ws + (4u  << 20));       // 8 MB
  ushort* VF   = (ushort*)(ws + (12u << 20));       // 8 MB (fragment order)
  ushort* BASE = (ushort*)(ws + (20u << 20));       // 2 MB
  ushort* Qb   = (ushort*)(ws + (22u << 20));       // 2 MB
  ushort* KF   = (ushort*)(ws + (24u << 20));       // 2 MB (fragment order)
  ushort* KVU  = (ushort*)(ws + (26u << 20));       // 8 MB
  ushort* WUT  = (ushort*)(ws + (34u << 20));
  ushort* WVT  = (ushort*)(ws + (34u << 20) + 512*256*2);
  ushort* WBT  = (ushort*)(ws + (34u << 20) + 2*512*256*2);
  ushort* WOT  = (ushort*)(ws + (34u << 20) + 2*512*256*2 + 128*256*2);
  float*  WREP = (float*)(ws + (35u << 20));        // 128 KB

  ln_kernel<<<2048, 256, 0, stream>>>(query, ln_w, ln_b, X);
  prep_kernel<<<1792, 256, 0, stream>>>(Wu, Wv, Wbase, Wo, w_rel,
                                        WUT, WVT, WBT, WOT, WREP);
  gemm_kernel<0><<<dim3(64, 8), 256, 0, stream>>>(X, WUT, bu, U, 8192, 512, 256);
  gemm_kernel<2><<<dim3(64, 8), 256, 0, stream>>>(X, WVT, bv, VF, 8192, 512, 256);
  gemm_kernel<0><<<dim3(64, 2), 256, 0, stream>>>(X, WBT, bbase, BASE, 8192, 128, 256);
  rope_kernel<<<2048, 256, 0, stream>>>(BASE, q_w, q_b, k_w, k_b, Qb, KF);
  attn_kernel<<<dim3(64, 4, 2), 256, 0, stream>>>(Qb, KF, VF, U, WREP, KVU);
  gemm_kernel<1><<<dim3(64, 4), 256, 0, stream>>>(KVU, WOT, bo, out, 8192, 256, 512);
}